// Round 1
// baseline (53042.047 us; speedup 1.0000x reference)
//
#include <hip/hip_runtime.h>
#include <math.h>

#define B_   64
#define T_   256
#define D_   1024
#define H_   512
#define S_   32
#define A_   64
#define OBS_ 1024
#define OUTD 1216   // 1024 + 6*32

__device__ __forceinline__ float sigmoidf_(float x) { return 1.0f / (1.0f + expf(-x)); }
__device__ __forceinline__ float softplusf_(float x) { return (x > 20.0f) ? x : log1pf(expf(x)); }

// ---------------------------------------------------------------------------
// k_init: zero deter buffer 0, compute emb_T for t=0 (stoch0 == 0).
// grid 256 x (64,4): thread (b=tx, j=bid*4+ty)
// ---------------------------------------------------------------------------
__global__ void k_init(const float* __restrict__ act, const float* __restrict__ W_sa,
                       const float* __restrict__ b_sa, float* __restrict__ emb_T,
                       float* __restrict__ deter0) {
    int b = threadIdx.x;
    int j = blockIdx.x * 4 + threadIdx.y;
    float acc = b_sa[j];
    const float* w = W_sa + (size_t)j * 96 + 32;   // act part of concat([stoch, act])
    const float* a = act + (size_t)b * T_ * A_;    // t = 0
#pragma unroll 8
    for (int c = 0; c < 64; ++c) acc += a[c] * w[c];
    emb_T[j * 64 + b] = fmaxf(acc, 0.0f);
    deter0[j * 64 + b] = 0.0f;
}

// ---------------------------------------------------------------------------
// k_gru: blocks [0,256): deter_out[j][b] = GRU(emb, deter_in) for j=bid*4+ty
//        blocks [256,272): transpose obs[:,t,:] -> obs_T[k][b]
// ---------------------------------------------------------------------------
__global__ void k_gru(int t,
                      const float* __restrict__ emb_T, const float* __restrict__ det_in,
                      float* __restrict__ det_out,
                      const float* __restrict__ W_ih, const float* __restrict__ b_ih,
                      const float* __restrict__ W_hh, const float* __restrict__ b_hh,
                      const float* __restrict__ obs, float* __restrict__ obs_T) {
    __shared__ float tile[64][65];
    if (blockIdx.x >= 256) {
        int kb = (blockIdx.x - 256) * 64;
        int tx = threadIdx.x, ty = threadIdx.y;
        for (int b = ty; b < 64; b += 4)
            tile[b][tx] = obs[(size_t)b * T_ * OBS_ + (size_t)t * OBS_ + kb + tx];
        __syncthreads();
        for (int kk = ty; kk < 64; kk += 4)
            obs_T[(size_t)(kb + kk) * 64 + tx] = tile[tx][kk];
        return;
    }
    int b = threadIdx.x;
    int j = blockIdx.x * 4 + threadIdx.y;
    const float4* wr = (const float4*)(W_ih + (size_t)j * 1024);
    const float4* wz = (const float4*)(W_ih + (size_t)(j + 1024) * 1024);
    const float4* wn = (const float4*)(W_ih + (size_t)(j + 2048) * 1024);
    const float4* vr = (const float4*)(W_hh + (size_t)j * 1024);
    const float4* vz = (const float4*)(W_hh + (size_t)(j + 1024) * 1024);
    const float4* vn = (const float4*)(W_hh + (size_t)(j + 2048) * 1024);
    float ir = 0.f, iz = 0.f, inn = 0.f, hr = 0.f, hz = 0.f, hn = 0.f;
#pragma unroll 2
    for (int k4 = 0; k4 < 256; ++k4) {
        float4 a = wr[k4], c = wz[k4], e = wn[k4];
        float4 f = vr[k4], g = vz[k4], m = vn[k4];
        int k = k4 * 4;
        float x0 = emb_T[(k + 0) * 64 + b], x1 = emb_T[(k + 1) * 64 + b];
        float x2 = emb_T[(k + 2) * 64 + b], x3 = emb_T[(k + 3) * 64 + b];
        float h0 = det_in[(k + 0) * 64 + b], h1 = det_in[(k + 1) * 64 + b];
        float h2 = det_in[(k + 2) * 64 + b], h3 = det_in[(k + 3) * 64 + b];
        ir  += x0 * a.x + x1 * a.y + x2 * a.z + x3 * a.w;
        iz  += x0 * c.x + x1 * c.y + x2 * c.z + x3 * c.w;
        inn += x0 * e.x + x1 * e.y + x2 * e.z + x3 * e.w;
        hr  += h0 * f.x + h1 * f.y + h2 * f.z + h3 * f.w;
        hz  += h0 * g.x + h1 * g.y + h2 * g.z + h3 * g.w;
        hn  += h0 * m.x + h1 * m.y + h2 * m.z + h3 * m.w;
    }
    float rr = sigmoidf_(ir + b_ih[j] + hr + b_hh[j]);
    float zz = sigmoidf_(iz + b_ih[j + 1024] + hz + b_hh[j + 1024]);
    float nn = tanhf(inn + b_ih[j + 2048] + rr * (hn + b_hh[j + 2048]));
    float hprev = det_in[j * 64 + b];
    det_out[j * 64 + b] = (1.0f - zz) * nn + zz * hprev;
}

// ---------------------------------------------------------------------------
// k_hid: blocks [0,256): slot = bid*4+ty; slot<512 -> pm1, else qm1
//        blocks [256,272): write deter slice of out (coalesced along j)
// ---------------------------------------------------------------------------
__global__ void k_hid(int t, const float* __restrict__ det, const float* __restrict__ obs_T,
                      const float* __restrict__ Wp1, const float* __restrict__ bp1,
                      const float* __restrict__ Wq1, const float* __restrict__ bq1,
                      float* __restrict__ pm1_T, float* __restrict__ qm1_T,
                      float* __restrict__ out) {
    if (blockIdx.x >= 256) {
        int jb = (blockIdx.x - 256) * 64;
        int lane = threadIdx.x, ty = threadIdx.y;
        for (int b = ty; b < 64; b += 4)
            out[(size_t)b * T_ * OUTD + (size_t)t * OUTD + jb + lane] = det[(jb + lane) * 64 + b];
        return;
    }
    int b = threadIdx.x;
    int slot = blockIdx.x * 4 + threadIdx.y;
    if (slot < 512) {
        int h = slot;
        const float4* w = (const float4*)(Wp1 + (size_t)h * 1024);
        float acc = bp1[h];
#pragma unroll 2
        for (int k4 = 0; k4 < 256; ++k4) {
            float4 a = w[k4];
            int k = 4 * k4;
            acc += det[(k + 0) * 64 + b] * a.x + det[(k + 1) * 64 + b] * a.y
                 + det[(k + 2) * 64 + b] * a.z + det[(k + 3) * 64 + b] * a.w;
        }
        pm1_T[h * 64 + b] = fmaxf(acc, 0.0f);
    } else {
        int h = slot - 512;
        const float4* w1 = (const float4*)(Wq1 + (size_t)h * 2048);
        const float4* w2 = (const float4*)(Wq1 + (size_t)h * 2048 + 1024);
        float acc = bq1[h];
#pragma unroll 2
        for (int k4 = 0; k4 < 256; ++k4) {
            float4 a = w1[k4], c = w2[k4];
            int k = 4 * k4;
            acc += det[(k + 0) * 64 + b] * a.x + det[(k + 1) * 64 + b] * a.y
                 + det[(k + 2) * 64 + b] * a.z + det[(k + 3) * 64 + b] * a.w;
            acc += obs_T[(k + 0) * 64 + b] * c.x + obs_T[(k + 1) * 64 + b] * c.y
                 + obs_T[(k + 2) * 64 + b] * c.z + obs_T[(k + 3) * 64 + b] * c.w;
        }
        qm1_T[h * 64 + b] = fmaxf(acc, 0.0f);
    }
}

// ---------------------------------------------------------------------------
// k_head: one block per batch row b. pm2/qm2, stats, output writes,
//         q_stoch -> emb_T for step t+1 (fused; stoch never hits global).
// ---------------------------------------------------------------------------
__global__ void k_head(int t, const float* __restrict__ pm1_T, const float* __restrict__ qm1_T,
                       const float* __restrict__ Wp2, const float* __restrict__ bp2,
                       const float* __restrict__ Wq2, const float* __restrict__ bq2,
                       const float* __restrict__ W_sa, const float* __restrict__ b_sa,
                       const float* __restrict__ n_p, const float* __restrict__ n_q,
                       const float* __restrict__ act, float* __restrict__ out,
                       float* __restrict__ emb_T) {
    __shared__ float s_p[512], s_q[512], s_head[128], s_stoch[32], s_act[64];
    int b = blockIdx.x, tid = threadIdx.x;
    for (int i = tid; i < 512; i += 256) {
        s_p[i] = pm1_T[i * 64 + b];
        s_q[i] = qm1_T[i * 64 + b];
    }
    __syncthreads();
    if (tid < 128) {
        int o = tid & 63;
        bool isq = tid >= 64;
        const float* W = (isq ? Wq2 : Wp2) + (size_t)o * 512;
        const float* src = isq ? s_q : s_p;
        float acc = isq ? bq2[o] : bp2[o];
#pragma unroll 4
        for (int k = 0; k < 512; ++k) acc += src[k] * W[k];
        s_head[tid] = acc;
    }
    __syncthreads();
    if (tid < 64) {
        int s = tid & 31;
        bool isq = tid >= 32;
        int base = isq ? 64 : 0;
        float mean = s_head[base + s];
        float raw  = s_head[base + 32 + s];
        float sd = softplusf_(raw) + 1e-5f;
        const float* nz = isq ? n_q : n_p;
        float noise = nz[(size_t)b * T_ * S_ + (size_t)t * S_ + s];
        float st = mean + sd * noise;
        float* o = out + (size_t)b * T_ * OUTD + (size_t)t * OUTD + 1024 + (isq ? 96 : 0);
        o[s] = mean;
        o[32 + s] = sd;
        o[64 + s] = st;
        if (isq) s_stoch[s] = st;
    }
    if (t + 1 < T_ && tid < 64)
        s_act[tid] = act[(size_t)b * T_ * A_ + (size_t)(t + 1) * A_ + tid];
    __syncthreads();
    if (t + 1 < T_) {
        for (int j = tid; j < 1024; j += 256) {
            const float4* w = (const float4*)(W_sa + (size_t)j * 96);
            float acc = b_sa[j];
#pragma unroll
            for (int c4 = 0; c4 < 8; ++c4) {
                float4 a = w[c4];
                int c = 4 * c4;
                acc += s_stoch[c] * a.x + s_stoch[c + 1] * a.y + s_stoch[c + 2] * a.z + s_stoch[c + 3] * a.w;
            }
#pragma unroll
            for (int c4 = 8; c4 < 24; ++c4) {
                float4 a = w[c4];
                int c = 4 * c4 - 32;
                acc += s_act[c] * a.x + s_act[c + 1] * a.y + s_act[c + 2] * a.z + s_act[c + 3] * a.w;
            }
            emb_T[j * 64 + b] = fmaxf(acc, 0.0f);
        }
    }
}

extern "C" void kernel_launch(void* const* d_in, const int* in_sizes, int n_in,
                              void* d_out, int out_size, void* d_ws, size_t ws_size,
                              hipStream_t stream) {
    const float* obs  = (const float*)d_in[0];
    const float* act  = (const float*)d_in[1];
    const float* n_p  = (const float*)d_in[2];
    const float* n_q  = (const float*)d_in[3];
    const float* W_sa = (const float*)d_in[4];
    const float* b_sa = (const float*)d_in[5];
    const float* W_ih = (const float*)d_in[6];
    const float* b_ih = (const float*)d_in[7];
    const float* W_hh = (const float*)d_in[8];
    const float* b_hh = (const float*)d_in[9];
    const float* Wp1  = (const float*)d_in[10];
    const float* bp1  = (const float*)d_in[11];
    const float* Wp2  = (const float*)d_in[12];
    const float* bp2  = (const float*)d_in[13];
    const float* Wq1  = (const float*)d_in[14];
    const float* bq1  = (const float*)d_in[15];
    const float* Wq2  = (const float*)d_in[16];
    const float* bq2  = (const float*)d_in[17];
    float* out = (float*)d_out;

    float* ws    = (float*)d_ws;
    float* dT0   = ws;            // [1024][64]
    float* dT1   = ws + 65536;    // [1024][64]
    float* emb_T = ws + 131072;   // [1024][64]
    float* obs_T = ws + 196608;   // [1024][64]
    float* pm1_T = ws + 262144;   // [512][64]
    float* qm1_T = ws + 294912;   // [512][64]  (end: 327680 floats = 1.25 MB)

    dim3 blk(64, 4);
    k_init<<<256, blk, 0, stream>>>(act, W_sa, b_sa, emb_T, dT0);
    for (int t = 0; t < T_; ++t) {
        float* din  = (t & 1) ? dT1 : dT0;
        float* dout = (t & 1) ? dT0 : dT1;
        k_gru<<<272, blk, 0, stream>>>(t, emb_T, din, dout, W_ih, b_ih, W_hh, b_hh, obs, obs_T);
        k_hid<<<272, blk, 0, stream>>>(t, dout, obs_T, Wp1, bp1, Wq1, bq1, pm1_T, qm1_T, out);
        k_head<<<64, 256, 0, stream>>>(t, pm1_T, qm1_T, Wp2, bp2, Wq2, bq2, W_sa, b_sa,
                                       n_p, n_q, act, out, emb_T);
    }
}

// Round 2
// 10239.293 us; speedup vs baseline: 5.1802x; 5.1802x over previous
//
#include <hip/hip_runtime.h>
#include <math.h>

#define B_   64
#define T_   256
#define OUTD 1216

typedef unsigned short ushort_t;
typedef unsigned int   uint32;
typedef __attribute__((ext_vector_type(8))) short bfrag;   // 8 bf16
typedef __attribute__((ext_vector_type(4))) float f32x4;
typedef __attribute__((ext_vector_type(4))) unsigned short us4;

__device__ __forceinline__ float sigmoidf_(float x) { return 1.0f / (1.0f + __expf(-x)); }
__device__ __forceinline__ float softplusf_(float x) { return (x > 20.0f) ? x : log1pf(__expf(x)); }
__device__ __forceinline__ ushort_t f2bf(float f) {
    uint32 u = __float_as_uint(f);
    u += 0x7fffu + ((u >> 16) & 1u);
    return (ushort_t)(u >> 16);
}
__device__ __forceinline__ float bf2f(ushort_t u) { return __uint_as_float(((uint32)u) << 16); }

// ---------------------------------------------------------------------------
// kwprep: one-time weight conversion.
//  - Wih/Whh/Wp1/Wq1: straight fp32->bf16 (row-major = MFMA A-operand friendly)
//  - W2sw:  [head][g(64)][o(64)][8]  bf16, g*8+i = k index into Wp2/Wq2 rows
//  - Wsasw: [g(12)][j(1024)][8]      bf16, g*8+i = c index into W_sa rows
// ---------------------------------------------------------------------------
__global__ void kwprep(const float* __restrict__ Wih, const float* __restrict__ Whh,
                       const float* __restrict__ Wp1, const float* __restrict__ Wq1,
                       const float* __restrict__ Wp2, const float* __restrict__ Wq2,
                       const float* __restrict__ Wsa,
                       ushort_t* Wih_b, ushort_t* Whh_b, ushort_t* Wp1_b, ushort_t* Wq1_b,
                       ushort_t* W2sw, ushort_t* Wsasw) {
    int stride = gridDim.x * blockDim.x;
    int gid = blockIdx.x * blockDim.x + threadIdx.x;
    for (int i = gid; i < 3072 * 1024; i += stride) Wih_b[i] = f2bf(Wih[i]);
    for (int i = gid; i < 3072 * 1024; i += stride) Whh_b[i] = f2bf(Whh[i]);
    for (int i = gid; i < 512 * 1024; i += stride) Wp1_b[i] = f2bf(Wp1[i]);
    for (int i = gid; i < 512 * 2048; i += stride) Wq1_b[i] = f2bf(Wq1[i]);
    for (int i = gid; i < 65536; i += stride) {
        int head = i >> 15, g = (i >> 9) & 63, o = (i >> 3) & 63, ii = i & 7;
        const float* src = head ? Wq2 : Wp2;
        W2sw[i] = f2bf(src[o * 512 + g * 8 + ii]);
    }
    for (int i = gid; i < 98304; i += stride) {
        int g = i >> 13, j = (i >> 3) & 1023, ii = i & 7;
        Wsasw[i] = f2bf(Wsa[j * 96 + g * 8 + ii]);
    }
}

// ---------------------------------------------------------------------------
// kinit: emb(t=0) (stoch0 = 0) into swizzled layout; zero det_sw0/det_fp0.
// grid 256 x 256: gid -> (j = gid>>6, b = gid&63)
// ---------------------------------------------------------------------------
__global__ void kinit(const float* __restrict__ act, const float* __restrict__ Wsa,
                      const float* __restrict__ bsa,
                      ushort_t* emb_sw, ushort_t* det_sw0, float* det_fp0) {
    int gid = blockIdx.x * 256 + threadIdx.x;
    int j = gid >> 6, b = gid & 63;
    float acc = bsa[j];
    const float* a = act + (size_t)b * T_ * 64;
    const float* w = Wsa + j * 96 + 32;
#pragma unroll 8
    for (int c = 0; c < 64; ++c) acc += a[c] * w[c];
    emb_sw[((j >> 3) * 64 + b) * 8 + (j & 7)] = f2bf(fmaxf(acc, 0.f));
    det_sw0[gid] = 0;
    det_fp0[gid] = 0.f;
}

// ---------------------------------------------------------------------------
// kgru: blocks [0,64): MFMA GRU for output j-span 16 (all 3 gates, both mats,
//       K split over 4 waves, LDS 2-phase reduce, gate math, writes:
//       out deter slice, det_fp_out [j][b], det_sw_out (swizzled bf16)).
//       blocks [64,80): swizzle obs[:,t,:] -> obs_sw for this step's khid.
// ---------------------------------------------------------------------------
__global__ __launch_bounds__(256) void kgru(int t,
        const ushort_t* __restrict__ Wih, const ushort_t* __restrict__ Whh,
        const float* __restrict__ bih, const float* __restrict__ bhh,
        const ushort_t* __restrict__ emb_sw, const ushort_t* __restrict__ det_sw_in,
        const float* __restrict__ det_fp_in,
        ushort_t* __restrict__ det_sw_out, float* __restrict__ det_fp_out,
        const float* __restrict__ obs, ushort_t* __restrict__ obs_sw,
        float* __restrict__ out) {
    if (blockIdx.x >= 64) {
        int kb = (blockIdx.x - 64) * 64;
        int tx = threadIdx.x & 63, ty = threadIdx.x >> 6;
        for (int b = ty; b < 64; b += 4) {
            int k = kb + tx;
            float v = obs[((size_t)b * T_ + t) * 1024 + k];
            obs_sw[((k >> 3) * 64 + b) * 8 + (k & 7)] = f2bf(v);
        }
        return;
    }
    __shared__ float red[2 * 24 * 256];   // 48 KB, 2 reduce slots x 24 tiles
    const int tid = threadIdx.x;
    const int lane = tid & 63, w = tid >> 6;
    const int m = lane & 15, quad = lane >> 4;
    const int j0 = blockIdx.x * 16;

    f32x4 acc[2][3][4];
#pragma unroll
    for (int a2 = 0; a2 < 2; ++a2)
#pragma unroll
        for (int g = 0; g < 3; ++g)
#pragma unroll
            for (int n = 0; n < 4; ++n) acc[a2][g][n] = (f32x4){0.f, 0.f, 0.f, 0.f};

    const int kb0 = w * 256;
    const ushort_t* arow[2][3];
#pragma unroll
    for (int g = 0; g < 3; ++g) {
        arow[0][g] = Wih + (size_t)(g * 1024 + j0 + m) * 1024 + kb0 + quad * 8;
        arow[1][g] = Whh + (size_t)(g * 1024 + j0 + m) * 1024 + kb0 + quad * 8;
    }
    const ushort_t* bx = emb_sw + ((kb0 >> 3) + quad) * 512 + m * 8;
    const ushort_t* bh = det_sw_in + ((kb0 >> 3) + quad) * 512 + m * 8;

#pragma unroll
    for (int it = 0; it < 8; ++it) {
        bfrag a[2][3], vx[4], vh[4];
#pragma unroll
        for (int g = 0; g < 3; ++g) {
            a[0][g] = *(const bfrag*)(arow[0][g] + it * 32);
            a[1][g] = *(const bfrag*)(arow[1][g] + it * 32);
        }
#pragma unroll
        for (int n = 0; n < 4; ++n) {
            vx[n] = *(const bfrag*)(bx + it * 2048 + n * 128);
            vh[n] = *(const bfrag*)(bh + it * 2048 + n * 128);
        }
#pragma unroll
        for (int g = 0; g < 3; ++g)
#pragma unroll
            for (int n = 0; n < 4; ++n) {
                acc[0][g][n] = __builtin_amdgcn_mfma_f32_16x16x32_bf16(a[0][g], vx[n], acc[0][g][n], 0, 0, 0);
                acc[1][g][n] = __builtin_amdgcn_mfma_f32_16x16x32_bf16(a[1][g], vh[n], acc[1][g][n], 0, 0, 0);
            }
    }

    // two-phase cross-wave reduction (waves 1,3 dump; waves 0,2 add)
    if (w & 1) {
        float* dst = red + (w >> 1) * 6144;
#pragma unroll
        for (int a2 = 0; a2 < 2; ++a2)
#pragma unroll
            for (int g = 0; g < 3; ++g)
#pragma unroll
                for (int n = 0; n < 4; ++n)
                    *(f32x4*)(dst + ((a2 * 3 + g) * 4 + n) * 256 + lane * 4) = acc[a2][g][n];
    }
    __syncthreads();
    if (!(w & 1)) {
        float* dst = red + (w >> 1) * 6144;
#pragma unroll
        for (int a2 = 0; a2 < 2; ++a2)
#pragma unroll
            for (int g = 0; g < 3; ++g)
#pragma unroll
                for (int n = 0; n < 4; ++n) {
                    float* pp = dst + ((a2 * 3 + g) * 4 + n) * 256 + lane * 4;
                    f32x4 v = *(const f32x4*)pp;
                    v += acc[a2][g][n];
                    *(f32x4*)pp = v;
                }
    }
    __syncthreads();

    // gate phase: thread -> (b = tid>>2, jq = tid&3), 4 consecutive j each
    int b = tid >> 2, jq = tid & 3;
    int nt = b >> 4, bl = b & 15;
    int lsrc = (jq * 16 + bl) * 4;
    float gg[2][3][4];
#pragma unroll
    for (int a2 = 0; a2 < 2; ++a2)
#pragma unroll
        for (int g = 0; g < 3; ++g) {
            f32x4 v0 = *(const f32x4*)(red + ((a2 * 3 + g) * 4 + nt) * 256 + lsrc);
            f32x4 v1 = *(const f32x4*)(red + 6144 + ((a2 * 3 + g) * 4 + nt) * 256 + lsrc);
#pragma unroll
            for (int i = 0; i < 4; ++i) gg[a2][g][i] = v0[i] + v1[i];
        }
    f32x4 bi[3], bh2[3];
#pragma unroll
    for (int g = 0; g < 3; ++g) {
        bi[g] = *(const f32x4*)(bih + g * 1024 + j0 + jq * 4);
        bh2[g] = *(const f32x4*)(bhh + g * 1024 + j0 + jq * 4);
    }
    f32x4 h4;
    us4 dq;
#pragma unroll
    for (int i = 0; i < 4; ++i) {
        int j = j0 + jq * 4 + i;
        float r = sigmoidf_(gg[0][0][i] + bi[0][i] + gg[1][0][i] + bh2[0][i]);
        float z = sigmoidf_(gg[0][1][i] + bi[1][i] + gg[1][1][i] + bh2[1][i]);
        float n = tanhf(gg[0][2][i] + bi[2][i] + r * (gg[1][2][i] + bh2[2][i]));
        float hp = det_fp_in[j * 64 + b];
        float h = (1.f - z) * n + z * hp;
        h4[i] = h;
        dq[i] = f2bf(h);
        det_fp_out[j * 64 + b] = h;
    }
    *(f32x4*)(out + ((size_t)b * T_ + t) * OUTD + j0 + jq * 4) = h4;
    int kbase = j0 + jq * 4;
    *(us4*)(det_sw_out + ((kbase >> 3) * 64 + b) * 8 + (kbase & 7)) = dq;
}

// ---------------------------------------------------------------------------
// khid: blocks [0,32): pm1 (K=1024), blocks [32,64): qm1 (K=2048, det|obs).
//       Same MFMA k-split structure; writes row-major fp32 [b][512] with relu.
// ---------------------------------------------------------------------------
__global__ __launch_bounds__(256) void khid(
        const ushort_t* __restrict__ Wp1b, const float* __restrict__ bp1,
        const ushort_t* __restrict__ Wq1b, const float* __restrict__ bq1,
        const ushort_t* __restrict__ det_sw, const ushort_t* __restrict__ obs_sw,
        float* __restrict__ pm1, float* __restrict__ qm1) {
    __shared__ float red[4 * 4 * 256];  // 16 KB
    const int tid = threadIdx.x;
    const int lane = tid & 63, w = tid >> 6;
    const int m = lane & 15, quad = lane >> 4;
    const bool isq = blockIdx.x >= 32;
    const int j0 = (isq ? blockIdx.x - 32 : blockIdx.x) * 16;

    f32x4 acc[4];
#pragma unroll
    for (int n = 0; n < 4; ++n) acc[n] = (f32x4){0.f, 0.f, 0.f, 0.f};

    if (!isq) {
        const ushort_t* ar = Wp1b + (size_t)(j0 + m) * 1024 + w * 256 + quad * 8;
        const ushort_t* bb = det_sw + ((w * 32) + quad) * 512 + m * 8;
#pragma unroll
        for (int it = 0; it < 8; ++it) {
            bfrag a = *(const bfrag*)(ar + it * 32);
#pragma unroll
            for (int n = 0; n < 4; ++n) {
                bfrag v = *(const bfrag*)(bb + it * 2048 + n * 128);
                acc[n] = __builtin_amdgcn_mfma_f32_16x16x32_bf16(a, v, acc[n], 0, 0, 0);
            }
        }
    } else {
        int kb0 = w * 512;
        const ushort_t* bsrc = (w < 2) ? det_sw : obs_sw;
        int kloc = (w < 2) ? kb0 : kb0 - 1024;
        const ushort_t* ar = Wq1b + (size_t)(j0 + m) * 2048 + kb0 + quad * 8;
        const ushort_t* bb = bsrc + ((kloc >> 3) + quad) * 512 + m * 8;
#pragma unroll
        for (int it = 0; it < 16; ++it) {
            bfrag a = *(const bfrag*)(ar + it * 32);
#pragma unroll
            for (int n = 0; n < 4; ++n) {
                bfrag v = *(const bfrag*)(bb + it * 2048 + n * 128);
                acc[n] = __builtin_amdgcn_mfma_f32_16x16x32_bf16(a, v, acc[n], 0, 0, 0);
            }
        }
    }
#pragma unroll
    for (int n = 0; n < 4; ++n)
        *(f32x4*)(red + (w * 4 + n) * 256 + lane * 4) = acc[n];
    __syncthreads();

    int b = tid >> 2, jq = tid & 3;
    int nt = b >> 4, lsrc = (jq * 16 + (b & 15)) * 4;
    f32x4 s = (f32x4){0.f, 0.f, 0.f, 0.f};
#pragma unroll
    for (int w2 = 0; w2 < 4; ++w2) s += *(const f32x4*)(red + (w2 * 4 + nt) * 256 + lsrc);
    f32x4 bv = *(const f32x4*)((isq ? bq1 : bp1) + j0 + jq * 4);
    f32x4 r;
#pragma unroll
    for (int i = 0; i < 4; ++i) r[i] = fmaxf(s[i] + bv[i], 0.f);
    *(f32x4*)((isq ? qm1 : pm1) + (size_t)b * 512 + j0 + jq * 4) = r;
}

// ---------------------------------------------------------------------------
// khead: one block per batch b. pm2/qm2 (swizzled bf16 weights), stats,
//        output stat writes, q_stoch -> emb(t+1) in swizzled layout.
// ---------------------------------------------------------------------------
__global__ __launch_bounds__(256) void khead(int t,
        const float* __restrict__ pm1, const float* __restrict__ qm1,
        const float* __restrict__ bp2, const float* __restrict__ bq2,
        const ushort_t* __restrict__ W2sw, const ushort_t* __restrict__ Wsasw,
        const float* __restrict__ bsa,
        const float* __restrict__ n_p, const float* __restrict__ n_q,
        const float* __restrict__ act,
        float* __restrict__ out, ushort_t* __restrict__ emb_sw) {
    __shared__ float sh[1024 + 128 + 96];
    float* s_p = sh;
    float* s_q = sh + 512;
    float* s_head = sh + 1024;
    float* s_in = sh + 1152;   // [0,32) stoch, [32,96) act(t+1)
    const int b = blockIdx.x, tid = threadIdx.x;
    if (tid < 128) ((f32x4*)s_p)[tid] = ((const f32x4*)(pm1 + (size_t)b * 512))[tid];
    else ((f32x4*)s_q)[tid - 128] = ((const f32x4*)(qm1 + (size_t)b * 512))[tid - 128];
    if (t + 1 < T_ && tid < 64) s_in[32 + tid] = act[((size_t)b * T_ + t + 1) * 64 + tid];
    __syncthreads();
    if (tid < 128) {
        int head = tid >> 6, o = tid & 63;
        const ushort_t* wp = W2sw + head * 32768 + o * 8;
        const float* hv = head ? s_q : s_p;
        float acc2 = (head ? bq2 : bp2)[o];
#pragma unroll 4
        for (int g = 0; g < 64; ++g) {
            bfrag w8 = *(const bfrag*)(wp + g * 512);
#pragma unroll
            for (int i2 = 0; i2 < 8; ++i2) acc2 += hv[g * 8 + i2] * bf2f((ushort_t)w8[i2]);
        }
        s_head[tid] = acc2;
    }
    __syncthreads();
    if (tid < 64) {
        int s = tid & 31, isq = tid >> 5;
        float mean = s_head[isq * 64 + s];
        float raw = s_head[isq * 64 + 32 + s];
        float sd = softplusf_(raw) + 1e-5f;
        float noise = (isq ? n_q : n_p)[((size_t)b * T_ + t) * 32 + s];
        float st = mean + sd * noise;
        float* o = out + ((size_t)b * T_ + t) * OUTD + 1024 + isq * 96;
        o[s] = mean;
        o[32 + s] = sd;
        o[64 + s] = st;
        if (isq) s_in[s] = st;
    }
    __syncthreads();
    if (t + 1 < T_) {
#pragma unroll
        for (int q = 0; q < 4; ++q) {
            int j = q * 256 + tid;
            float acc2 = bsa[j];
#pragma unroll
            for (int g = 0; g < 12; ++g) {
                bfrag w8 = *(const bfrag*)(Wsasw + ((size_t)g * 1024 + j) * 8);
#pragma unroll
                for (int i2 = 0; i2 < 8; ++i2) acc2 += s_in[g * 8 + i2] * bf2f((ushort_t)w8[i2]);
            }
            emb_sw[((j >> 3) * 64 + b) * 8 + (j & 7)] = f2bf(fmaxf(acc2, 0.f));
        }
    }
}

extern "C" void kernel_launch(void* const* d_in, const int* in_sizes, int n_in,
                              void* d_out, int out_size, void* d_ws, size_t ws_size,
                              hipStream_t stream) {
    const float* obs = (const float*)d_in[0];
    const float* act = (const float*)d_in[1];
    const float* n_p = (const float*)d_in[2];
    const float* n_q = (const float*)d_in[3];
    const float* W_sa = (const float*)d_in[4];
    const float* b_sa = (const float*)d_in[5];
    const float* W_ih = (const float*)d_in[6];
    const float* b_ih = (const float*)d_in[7];
    const float* W_hh = (const float*)d_in[8];
    const float* b_hh = (const float*)d_in[9];
    const float* Wp1 = (const float*)d_in[10];
    const float* bp1 = (const float*)d_in[11];
    const float* Wp2 = (const float*)d_in[12];
    const float* bp2 = (const float*)d_in[13];
    const float* Wq1 = (const float*)d_in[14];
    const float* bq1 = (const float*)d_in[15];
    const float* Wq2 = (const float*)d_in[16];
    const float* bq2 = (const float*)d_in[17];
    float* out = (float*)d_out;

    char* p = (char*)d_ws;
    ushort_t* Wih_b = (ushort_t*)p;  p += (size_t)3145728 * 2;
    ushort_t* Whh_b = (ushort_t*)p;  p += (size_t)3145728 * 2;
    ushort_t* Wp1_b = (ushort_t*)p;  p += (size_t)524288 * 2;
    ushort_t* Wq1_b = (ushort_t*)p;  p += (size_t)1048576 * 2;
    ushort_t* W2sw  = (ushort_t*)p;  p += (size_t)65536 * 2;
    ushort_t* Wsasw = (ushort_t*)p;  p += (size_t)98304 * 2;
    ushort_t* emb_sw = (ushort_t*)p; p += (size_t)65536 * 2;
    ushort_t* obs_sw = (ushort_t*)p; p += (size_t)65536 * 2;
    ushort_t* det_sw0 = (ushort_t*)p; p += (size_t)65536 * 2;
    ushort_t* det_sw1 = (ushort_t*)p; p += (size_t)65536 * 2;
    float* det_fp0 = (float*)p; p += (size_t)65536 * 4;
    float* det_fp1 = (float*)p; p += (size_t)65536 * 4;
    float* pm1 = (float*)p; p += (size_t)32768 * 4;
    float* qm1 = (float*)p; p += (size_t)32768 * 4;

    kwprep<<<1024, 256, 0, stream>>>(W_ih, W_hh, Wp1, Wq1, Wp2, Wq2, W_sa,
                                     Wih_b, Whh_b, Wp1_b, Wq1_b, W2sw, Wsasw);
    kinit<<<256, 256, 0, stream>>>(act, W_sa, b_sa, emb_sw, det_sw0, det_fp0);

    for (int t = 0; t < T_; ++t) {
        ushort_t* dsw_in = (t & 1) ? det_sw1 : det_sw0;
        ushort_t* dsw_out = (t & 1) ? det_sw0 : det_sw1;
        float* dfp_in = (t & 1) ? det_fp1 : det_fp0;
        float* dfp_out = (t & 1) ? det_fp0 : det_fp1;
        kgru<<<80, 256, 0, stream>>>(t, Wih_b, Whh_b, b_ih, b_hh, emb_sw, dsw_in, dfp_in,
                                     dsw_out, dfp_out, obs, obs_sw, out);
        khid<<<64, 256, 0, stream>>>(Wp1_b, bp1, Wq1_b, bq1, dsw_out, obs_sw, pm1, qm1);
        khead<<<64, 256, 0, stream>>>(t, pm1, qm1, bp2, bq2, W2sw, Wsasw, b_sa,
                                      n_p, n_q, act, out, emb_sw);
    }
}